// Round 4
// baseline (1265.848 us; speedup 1.0000x reference)
//
#include <hip/hip_runtime.h>

#define MTOT (16 * 4096)   // 65536 queries
#define KDIM 256           // vector dim
#define CBSZ 1024          // codebook size

using half8  = _Float16 __attribute__((ext_vector_type(8)));
using f32x16 = float    __attribute__((ext_vector_type(16)));

// ---------------------------------------------------------------------------
// Kernel 1 (prep): codebook -> fragment-major fp16 hi/lo + squared norms.
// cbF layout (half8 units): [panel(32)][kc(16)][term(2)][lane(64)]
//   lane = g*32 + (c&31), holds cb[c][kc*16 + g*8 .. +8]
// ---------------------------------------------------------------------------
__global__ void vq_prep(const float* __restrict__ cb,
                        _Float16* __restrict__ cbF, float* __restrict__ hn) {
    const int flat = blockIdx.x * 256 + threadIdx.x;   // 32768 total
    const int c = flat >> 5;
    const int grp = flat & 31;
    const int kc = grp >> 1, g = grp & 1;
    const float* p = cb + (size_t)c * KDIM + grp * 8;
    float4 f0 = *reinterpret_cast<const float4*>(p);
    float4 f1 = *reinterpret_cast<const float4*>(p + 4);
    float fv[8] = {f0.x, f0.y, f0.z, f0.w, f1.x, f1.y, f1.z, f1.w};
    half8 h, l;
    float s = 0.0f;
    #pragma unroll
    for (int j = 0; j < 8; ++j) {
        h[j] = (_Float16)fv[j];
        l[j] = (_Float16)(fv[j] - (float)h[j]);
        s += fv[j] * fv[j];
    }
    const int pan = c >> 5, m = c & 31;
    const int lane = g * 32 + m;
    const size_t off = (((size_t)pan * 16 + kc) * 2 + 0) * 64 + lane;  // half8 units
    *reinterpret_cast<half8*>(cbF + off * 8) = h;
    *reinterpret_cast<half8*>(cbF + (off + 64) * 8) = l;               // term=1 (+64 half8)
    #pragma unroll
    for (int d = 16; d; d >>= 1) s += __shfl_xor(s, d);
    if (grp == 0) hn[c] = s;
}

// ---------------------------------------------------------------------------
// Kernel 2: MFMA distance GEMM + argmin.  512 threads, 128 queries/block.
// Queries staged in LDS as fp16 hi/lo fragment-major (kc-XOR-swizzled slots).
// Wave w covers codewords w*128..w*128+127 (4 panels as 2 pairs).
// ---------------------------------------------------------------------------
__global__ __launch_bounds__(512, 2)
void vq_main(const float* __restrict__ A,          // z_e [MTOT][KDIM] fp32
             const _Float16* __restrict__ cbF,     // fragment-major codebook
             const float* __restrict__ hn,         // [CBSZ] norms
             float* __restrict__ out_idx_f,
             int* __restrict__ out_idx_i) {
    // qF layout (half8 units): [qg(4)][kc(16)][term(2)][slot(64)]
    __shared__ _Float16 qF[4 * 16 * 2 * 64 * 8];   // 128 KB
    __shared__ float hs[CBSZ];                      // 4 KB
    __shared__ float smin[8][128];                  // 4 KB
    __shared__ int   simin[8][128];                 // 4 KB

    const int tid = threadIdx.x;
    const int qbase = blockIdx.x * 128;

    // ---- stage queries: fp32 -> fp16 hi/lo fragments in LDS ----
    #pragma unroll
    for (int it = 0; it < 8; ++it) {
        const int flat = it * 512 + tid;            // 4096 groups
        const int q = flat >> 5;                    // 0..127
        const int grp = flat & 31;
        const int kc = grp >> 1, g = grp & 1;
        const float* p = A + (size_t)(qbase + q) * KDIM + grp * 8;
        float4 f0 = *reinterpret_cast<const float4*>(p);
        float4 f1 = *reinterpret_cast<const float4*>(p + 4);
        float fv[8] = {f0.x, f0.y, f0.z, f0.w, f1.x, f1.y, f1.z, f1.w};
        half8 h, l;
        #pragma unroll
        for (int j = 0; j < 8; ++j) {
            h[j] = (_Float16)fv[j];
            l[j] = (_Float16)(fv[j] - (float)h[j]);
        }
        const int qg = q >> 5;
        const int lw = g * 32 + (q & 31);
        const int sl = lw ^ (kc & 7);               // swizzled 16B slot
        _Float16* dst = qF + (((qg * 16 + kc) * 2 + 0) * 64 + sl) * 8;
        *reinterpret_cast<half8*>(dst) = h;
        *reinterpret_cast<half8*>(dst + 512) = l;   // term=1: +64 half8 = +512 halves
    }
    for (int i = tid; i < CBSZ; i += 512) hs[i] = hn[i];
    __syncthreads();

    const int lane = tid & 63;
    const int wave = tid >> 6;
    const int m31 = lane & 31;
    const int g = lane >> 5;

    float minv[4];
    int   mini[4];
    #pragma unroll
    for (int qg = 0; qg < 4; ++qg) { minv[qg] = 3.4e38f; mini[qg] = 0; }

    #pragma unroll
    for (int pp = 0; pp < 2; ++pp) {
        const int pa = wave * 4 + pp * 2;           // panel pair pa, pa+1

        f32x16 acc[2][4];
        #pragma unroll
        for (int P = 0; P < 2; ++P)
            #pragma unroll
            for (int qg = 0; qg < 4; ++qg) acc[P][qg] = (f32x16){};

        // A-fragment address helper (half8 units)
        #define AFRAG(p_, kc_, t_) \
            (*reinterpret_cast<const half8*>(cbF + ((((size_t)(p_) * 16 + (kc_)) * 2 + (t_)) * 64 + lane) * 8))

        half8 Aha = AFRAG(pa, 0, 0), Ala = AFRAG(pa, 0, 1);
        half8 Ahb = AFRAG(pa + 1, 0, 0), Alb = AFRAG(pa + 1, 0, 1);

        #pragma unroll
        for (int kc = 0; kc < 16; ++kc) {
            // B fragments from LDS (swizzled slots)
            half8 bh[4], bl[4];
            const int sl = lane ^ (kc & 7);
            #pragma unroll
            for (int qg = 0; qg < 4; ++qg) {
                const _Float16* qb = qF + (((qg * 16 + kc) * 2 + 0) * 64 + sl) * 8;
                bh[qg] = *reinterpret_cast<const half8*>(qb);
                bl[qg] = *reinterpret_cast<const half8*>(qb + 512);   // +64 half8
            }
            // prefetch next kc's A fragments
            half8 nAha, nAla, nAhb, nAlb;
            if (kc < 15) {
                nAha = AFRAG(pa, kc + 1, 0); nAla = AFRAG(pa, kc + 1, 1);
                nAhb = AFRAG(pa + 1, kc + 1, 0); nAlb = AFRAG(pa + 1, kc + 1, 1);
            }
            #pragma unroll
            for (int qg = 0; qg < 4; ++qg) {
                acc[0][qg] = __builtin_amdgcn_mfma_f32_32x32x16_f16(Aha, bh[qg], acc[0][qg], 0, 0, 0);
                acc[1][qg] = __builtin_amdgcn_mfma_f32_32x32x16_f16(Ahb, bh[qg], acc[1][qg], 0, 0, 0);
            }
            #pragma unroll
            for (int qg = 0; qg < 4; ++qg) {
                acc[0][qg] = __builtin_amdgcn_mfma_f32_32x32x16_f16(Ala, bh[qg], acc[0][qg], 0, 0, 0);
                acc[1][qg] = __builtin_amdgcn_mfma_f32_32x32x16_f16(Alb, bh[qg], acc[1][qg], 0, 0, 0);
            }
            #pragma unroll
            for (int qg = 0; qg < 4; ++qg) {
                acc[0][qg] = __builtin_amdgcn_mfma_f32_32x32x16_f16(Aha, bl[qg], acc[0][qg], 0, 0, 0);
                acc[1][qg] = __builtin_amdgcn_mfma_f32_32x32x16_f16(Ahb, bl[qg], acc[1][qg], 0, 0, 0);
            }
            Aha = nAha; Ala = nAla; Ahb = nAhb; Alb = nAlb;
        }
        #undef AFRAG

        // epilogue: surrogate distance + running argmin (ascending codeword)
        #pragma unroll
        for (int P = 0; P < 2; ++P) {
            const int cwb = (pa + P) * 32 + 4 * g;
            #pragma unroll
            for (int qg = 0; qg < 4; ++qg) {
                #pragma unroll
                for (int r = 0; r < 16; ++r) {
                    const int cw = cwb + (r & 3) + 8 * (r >> 2);
                    float s = fmaf(-2.0f, acc[P][qg][r], hs[cw]);
                    if (s < minv[qg]) { minv[qg] = s; mini[qg] = cw; }
                }
            }
        }
    }

    // combine the two g-halves (tie -> lower index)
    #pragma unroll
    for (int qg = 0; qg < 4; ++qg) {
        float v = minv[qg]; int ix = mini[qg];
        float ov = __shfl_xor(v, 32);
        int oi = __shfl_xor(ix, 32);
        if (ov < v || (ov == v && oi < ix)) { v = ov; ix = oi; }
        if (g == 0) { smin[wave][qg * 32 + m31] = v; simin[wave][qg * 32 + m31] = ix; }
    }
    __syncthreads();

    // cross-wave reduce: wave order = ascending codeword blocks
    if (tid < 128) {
        float bv = smin[0][tid]; int bi = simin[0][tid];
        #pragma unroll
        for (int w = 1; w < 8; ++w) {
            float v = smin[w][tid]; int ii = simin[w][tid];
            if (v < bv || (v == bv && ii < bi)) { bv = v; bi = ii; }
        }
        out_idx_f[qbase + tid] = (float)bi;
        out_idx_i[qbase + tid] = bi;
    }
}

// ---------------------------------------------------------------------------
// Kernel 3: gather z_q = codebook[idx], per-block loss partials (no atomics).
// ---------------------------------------------------------------------------
#define GATHER_BLOCKS 2048
__global__ void vq_gather(const float* __restrict__ A, const float* __restrict__ cb,
                          const int* __restrict__ idx, float* __restrict__ zq,
                          float* __restrict__ partial) {
    const float4* A4  = reinterpret_cast<const float4*>(A);
    const float4* cb4 = reinterpret_cast<const float4*>(cb);
    float4* zq4 = reinterpret_cast<float4*>(zq);

    const int tg = blockIdx.x * 256 + threadIdx.x;
    float acc = 0.0f;
    #pragma unroll
    for (int it = 0; it < 8; ++it) {
        const size_t gi = (size_t)tg + (size_t)it * (GATHER_BLOCKS * 256);
        const int qq = (int)(gi >> 6);
        const int seg = (int)(gi & 63);
        const int c = idx[qq];                       // wave-uniform
        float4 cv = cb4[(size_t)c * 64 + seg];
        float4 zv = A4[gi];
        zq4[gi] = cv;
        float dx = cv.x - zv.x, dy = cv.y - zv.y, dz = cv.z - zv.z, dw = cv.w - zv.w;
        acc += dx * dx + dy * dy + dz * dz + dw * dw;
    }
    #pragma unroll
    for (int d = 32; d; d >>= 1) acc += __shfl_xor(acc, d);
    __shared__ float ps[4];
    if ((threadIdx.x & 63) == 0) ps[threadIdx.x >> 6] = acc;
    __syncthreads();
    if (threadIdx.x == 0)
        partial[blockIdx.x] = ps[0] + ps[1] + ps[2] + ps[3];
}

// ---------------------------------------------------------------------------
// Kernel 4: reduce partials -> loss = sum / (B*N*D)
// ---------------------------------------------------------------------------
__global__ void vq_finish(const float* __restrict__ partial, float* __restrict__ out_loss) {
    float s = 0.0f;
    #pragma unroll
    for (int it = 0; it < GATHER_BLOCKS / 256; ++it)
        s += partial[threadIdx.x + it * 256];
    #pragma unroll
    for (int d = 32; d; d >>= 1) s += __shfl_xor(s, d);
    __shared__ float ps[4];
    if ((threadIdx.x & 63) == 0) ps[threadIdx.x >> 6] = s;
    __syncthreads();
    if (threadIdx.x == 0)
        *out_loss = (ps[0] + ps[1] + ps[2] + ps[3]) * (1.0f / 16777216.0f);
}

extern "C" void kernel_launch(void* const* d_in, const int* in_sizes, int n_in,
                              void* d_out, int out_size, void* d_ws, size_t ws_size,
                              hipStream_t stream) {
    const float* z_e = (const float*)d_in[0];
    const float* cb  = (const float*)d_in[1];

    float* out   = (float*)d_out;
    float* zq    = out;
    float* oidx  = out + (size_t)MTOT * KDIM;
    float* oloss = out + (size_t)MTOT * KDIM + MTOT;

    char* ws = (char*)d_ws;
    _Float16* cbF = (_Float16*)ws;                               // 1 MB
    float* hn     = (float*)(ws + 1024 * 1024);                  // 4 KB
    int* iidx     = (int*)(ws + 1024 * 1024 + 4096);             // 256 KB
    float* part   = (float*)(ws + 1024 * 1024 + 4096 + 262144);  // 8 KB

    vq_prep<<<128, 256, 0, stream>>>(cb, cbF, hn);
    vq_main<<<MTOT / 128, 512, 0, stream>>>(z_e, cbF, hn, oidx, iidx);
    vq_gather<<<GATHER_BLOCKS, 256, 0, stream>>>(z_e, cb, iidx, zq, part);
    vq_finish<<<1, 256, 0, stream>>>(part, oloss);
}

// Round 5
// 485.656 us; speedup vs baseline: 2.6065x; 2.6065x over previous
//
#include <hip/hip_runtime.h>

#define MTOT (16 * 4096)   // 65536 queries
#define KDIM 256           // vector dim
#define CBSZ 1024          // codebook size

using half8  = _Float16 __attribute__((ext_vector_type(8)));
using f32x16 = float    __attribute__((ext_vector_type(16)));

// ---------------------------------------------------------------------------
// Kernel 1 (prep): codebook -> fragment-major fp16 hi/lo + squared norms.
// cbF layout (half8 units): [panel(32)][kc(16)][term(2)][lane(64)]
//   lane = g*32 + (c&31), holds cb[c][kc*16 + g*8 .. +8]
// ---------------------------------------------------------------------------
__global__ void vq_prep(const float* __restrict__ cb,
                        _Float16* __restrict__ cbF, float* __restrict__ hn) {
    const int flat = blockIdx.x * 256 + threadIdx.x;   // 32768 total
    const int c = flat >> 5;
    const int grp = flat & 31;
    const int kc = grp >> 1, g = grp & 1;
    const float* p = cb + (size_t)c * KDIM + grp * 8;
    float4 f0 = *reinterpret_cast<const float4*>(p);
    float4 f1 = *reinterpret_cast<const float4*>(p + 4);
    float fv[8] = {f0.x, f0.y, f0.z, f0.w, f1.x, f1.y, f1.z, f1.w};
    half8 h, l;
    float s = 0.0f;
    #pragma unroll
    for (int j = 0; j < 8; ++j) {
        h[j] = (_Float16)fv[j];
        l[j] = (_Float16)(fv[j] - (float)h[j]);
        s += fv[j] * fv[j];
    }
    const int pan = c >> 5, m = c & 31;
    const int lane = g * 32 + m;
    const size_t off = (((size_t)pan * 16 + kc) * 2 + 0) * 64 + lane;  // half8 units
    *reinterpret_cast<half8*>(cbF + off * 8) = h;
    *reinterpret_cast<half8*>(cbF + (off + 64) * 8) = l;               // term=1 (+64 half8)
    #pragma unroll
    for (int d = 16; d; d >>= 1) s += __shfl_xor(s, d);
    if (grp == 0) hn[c] = s;
}

// ---------------------------------------------------------------------------
// Kernel 2: MFMA distance GEMM + argmin.  512 threads, 128 queries/block.
// Queries staged in LDS (fp16 hi/lo fragment-major, kc-XOR-swizzled slots).
// Wave w owns codewords w*128..w*128+127 as 4 sequential panels.
// Register economy: acc[4 qg] = 64 regs per panel; A-frags from global cbF.
// ---------------------------------------------------------------------------
__global__ __launch_bounds__(512, 2)
void vq_main(const float* __restrict__ A,          // z_e [MTOT][KDIM] fp32
             const _Float16* __restrict__ cbF,     // fragment-major codebook
             const float* __restrict__ hn,         // [CBSZ] norms
             float* __restrict__ out_idx_f,
             int* __restrict__ out_idx_i) {
    // qF layout (half8 units): [qg(4)][kc(16)][term(2)][slot(64)]
    __shared__ _Float16 qF[4 * 16 * 2 * 64 * 8];   // 128 KB
    __shared__ float hs[CBSZ];                      // 4 KB
    __shared__ float smin[8][128];                  // 4 KB
    __shared__ int   simin[8][128];                 // 4 KB

    const int tid = threadIdx.x;
    const int qbase = blockIdx.x * 128;

    // ---- stage queries: fp32 -> fp16 hi/lo fragments in LDS ----
    #pragma unroll
    for (int it = 0; it < 8; ++it) {
        const int flat = it * 512 + tid;            // 4096 groups
        const int q = flat >> 5;                    // 0..127
        const int grp = flat & 31;
        const int kc = grp >> 1, g = grp & 1;
        const float* p = A + (size_t)(qbase + q) * KDIM + grp * 8;
        float4 f0 = *reinterpret_cast<const float4*>(p);
        float4 f1 = *reinterpret_cast<const float4*>(p + 4);
        float fv[8] = {f0.x, f0.y, f0.z, f0.w, f1.x, f1.y, f1.z, f1.w};
        half8 h, l;
        #pragma unroll
        for (int j = 0; j < 8; ++j) {
            h[j] = (_Float16)fv[j];
            l[j] = (_Float16)(fv[j] - (float)h[j]);
        }
        const int qg = q >> 5;
        const int lw = g * 32 + (q & 31);
        const int sl = lw ^ (kc & 7);               // swizzled 16B slot
        _Float16* dst = qF + (((qg * 16 + kc) * 2 + 0) * 64 + sl) * 8;
        *reinterpret_cast<half8*>(dst) = h;
        *reinterpret_cast<half8*>(dst + 512) = l;   // term=1: +64 half8 = +512 halves
    }
    for (int i = tid; i < CBSZ; i += 512) hs[i] = hn[i];
    __syncthreads();

    const int lane = tid & 63;
    const int wave = tid >> 6;
    const int m31 = lane & 31;
    const int g = lane >> 5;

    float minv[4];
    int   mini[4];
    #pragma unroll
    for (int qg = 0; qg < 4; ++qg) { minv[qg] = 3.4e38f; mini[qg] = 0; }

    for (int pi = 0; pi < 4; ++pi) {
        const int pan = wave * 4 + pi;              // one panel at a time

        f32x16 acc[4];
        #pragma unroll
        for (int qg = 0; qg < 4; ++qg) acc[qg] = (f32x16){};

        // A-fragment address helper (half8 units)
        #define AFRAG(kc_, t_) \
            (*reinterpret_cast<const half8*>(cbF + ((((size_t)pan * 16 + (kc_)) * 2 + (t_)) * 64 + lane) * 8))

        #pragma unroll
        for (int kc = 0; kc < 16; ++kc) {
            half8 Ah = AFRAG(kc, 0);
            half8 Al = AFRAG(kc, 1);
            // B fragments from LDS (swizzled slots)
            const int sl = lane ^ (kc & 7);
            half8 bh[4], bl[4];
            #pragma unroll
            for (int qg = 0; qg < 4; ++qg) {
                const _Float16* qb = qF + (((qg * 16 + kc) * 2 + 0) * 64 + sl) * 8;
                bh[qg] = *reinterpret_cast<const half8*>(qb);
                bl[qg] = *reinterpret_cast<const half8*>(qb + 512);   // +64 half8
            }
            #pragma unroll
            for (int qg = 0; qg < 4; ++qg)
                acc[qg] = __builtin_amdgcn_mfma_f32_32x32x16_f16(Ah, bh[qg], acc[qg], 0, 0, 0);
            #pragma unroll
            for (int qg = 0; qg < 4; ++qg)
                acc[qg] = __builtin_amdgcn_mfma_f32_32x32x16_f16(Al, bh[qg], acc[qg], 0, 0, 0);
            #pragma unroll
            for (int qg = 0; qg < 4; ++qg)
                acc[qg] = __builtin_amdgcn_mfma_f32_32x32x16_f16(Ah, bl[qg], acc[qg], 0, 0, 0);
        }
        #undef AFRAG

        // epilogue: surrogate distance + running argmin (ascending codeword)
        const int cwb = pan * 32 + 4 * g;
        #pragma unroll
        for (int qg = 0; qg < 4; ++qg) {
            #pragma unroll
            for (int r = 0; r < 16; ++r) {
                const int cw = cwb + (r & 3) + 8 * (r >> 2);
                float s = fmaf(-2.0f, acc[qg][r], hs[cw]);
                if (s < minv[qg]) { minv[qg] = s; mini[qg] = cw; }
            }
        }
    }

    // combine the two g-halves (tie -> lower index)
    #pragma unroll
    for (int qg = 0; qg < 4; ++qg) {
        float v = minv[qg]; int ix = mini[qg];
        float ov = __shfl_xor(v, 32);
        int oi = __shfl_xor(ix, 32);
        if (ov < v || (ov == v && oi < ix)) { v = ov; ix = oi; }
        if (g == 0) { smin[wave][qg * 32 + m31] = v; simin[wave][qg * 32 + m31] = ix; }
    }
    __syncthreads();

    // cross-wave reduce: wave order = ascending codeword blocks
    if (tid < 128) {
        float bv = smin[0][tid]; int bi = simin[0][tid];
        #pragma unroll
        for (int w = 1; w < 8; ++w) {
            float v = smin[w][tid]; int ii = simin[w][tid];
            if (v < bv || (v == bv && ii < bi)) { bv = v; bi = ii; }
        }
        out_idx_f[qbase + tid] = (float)bi;
        out_idx_i[qbase + tid] = bi;
    }
}

// ---------------------------------------------------------------------------
// Kernel 3: gather z_q = codebook[idx], per-block loss partials (no atomics).
// ---------------------------------------------------------------------------
#define GATHER_BLOCKS 2048
__global__ void vq_gather(const float* __restrict__ A, const float* __restrict__ cb,
                          const int* __restrict__ idx, float* __restrict__ zq,
                          float* __restrict__ partial) {
    const float4* A4  = reinterpret_cast<const float4*>(A);
    const float4* cb4 = reinterpret_cast<const float4*>(cb);
    float4* zq4 = reinterpret_cast<float4*>(zq);

    const int tg = blockIdx.x * 256 + threadIdx.x;
    float acc = 0.0f;
    #pragma unroll
    for (int it = 0; it < 8; ++it) {
        const size_t gi = (size_t)tg + (size_t)it * (GATHER_BLOCKS * 256);
        const int qq = (int)(gi >> 6);
        const int seg = (int)(gi & 63);
        const int c = idx[qq];                       // wave-uniform
        float4 cv = cb4[(size_t)c * 64 + seg];
        float4 zv = A4[gi];
        zq4[gi] = cv;
        float dx = cv.x - zv.x, dy = cv.y - zv.y, dz = cv.z - zv.z, dw = cv.w - zv.w;
        acc += dx * dx + dy * dy + dz * dz + dw * dw;
    }
    #pragma unroll
    for (int d = 32; d; d >>= 1) acc += __shfl_xor(acc, d);
    __shared__ float ps[4];
    if ((threadIdx.x & 63) == 0) ps[threadIdx.x >> 6] = acc;
    __syncthreads();
    if (threadIdx.x == 0)
        partial[blockIdx.x] = ps[0] + ps[1] + ps[2] + ps[3];
}

// ---------------------------------------------------------------------------
// Kernel 4: reduce partials -> loss = sum / (B*N*D)
// ---------------------------------------------------------------------------
__global__ void vq_finish(const float* __restrict__ partial, float* __restrict__ out_loss) {
    float s = 0.0f;
    #pragma unroll
    for (int it = 0; it < GATHER_BLOCKS / 256; ++it)
        s += partial[threadIdx.x + it * 256];
    #pragma unroll
    for (int d = 32; d; d >>= 1) s += __shfl_xor(s, d);
    __shared__ float ps[4];
    if ((threadIdx.x & 63) == 0) ps[threadIdx.x >> 6] = s;
    __syncthreads();
    if (threadIdx.x == 0)
        *out_loss = (ps[0] + ps[1] + ps[2] + ps[3]) * (1.0f / 16777216.0f);
}

extern "C" void kernel_launch(void* const* d_in, const int* in_sizes, int n_in,
                              void* d_out, int out_size, void* d_ws, size_t ws_size,
                              hipStream_t stream) {
    const float* z_e = (const float*)d_in[0];
    const float* cb  = (const float*)d_in[1];

    float* out   = (float*)d_out;
    float* zq    = out;
    float* oidx  = out + (size_t)MTOT * KDIM;
    float* oloss = out + (size_t)MTOT * KDIM + MTOT;

    char* ws = (char*)d_ws;
    _Float16* cbF = (_Float16*)ws;                               // 1 MB
    float* hn     = (float*)(ws + 1024 * 1024);                  // 4 KB
    int* iidx     = (int*)(ws + 1024 * 1024 + 4096);             // 256 KB
    float* part   = (float*)(ws + 1024 * 1024 + 4096 + 262144);  // 8 KB

    vq_prep<<<128, 256, 0, stream>>>(cb, cbF, hn);
    vq_main<<<MTOT / 128, 512, 0, stream>>>(z_e, cbF, hn, oidx, iidx);
    vq_gather<<<GATHER_BLOCKS, 256, 0, stream>>>(z_e, cb, iidx, zq, part);
    vq_finish<<<1, 256, 0, stream>>>(part, oloss);
}

// Round 6
// 485.520 us; speedup vs baseline: 2.6072x; 1.0003x over previous
//
#include <hip/hip_runtime.h>

#define MTOT (16 * 4096)   // 65536 queries
#define KDIM 256           // vector dim
#define CBSZ 1024          // codebook size

using half8  = _Float16 __attribute__((ext_vector_type(8)));
using f32x16 = float    __attribute__((ext_vector_type(16)));

// ---------------------------------------------------------------------------
// Kernel 1 (prep): codebook -> fragment-major fp16 hi/lo + squared norms.
// cbF layout (half8 units): [panel(32)][kc(16)][term(2)][lane(64)]
//   lane = g*32 + (c&31), holds cb[c][kc*16 + g*8 .. +8]
// ---------------------------------------------------------------------------
__global__ void vq_prep(const float* __restrict__ cb,
                        _Float16* __restrict__ cbF, float* __restrict__ hn) {
    const int flat = blockIdx.x * 256 + threadIdx.x;   // 32768 total
    const int c = flat >> 5;
    const int grp = flat & 31;
    const int kc = grp >> 1, g = grp & 1;
    const float* p = cb + (size_t)c * KDIM + grp * 8;
    float4 f0 = *reinterpret_cast<const float4*>(p);
    float4 f1 = *reinterpret_cast<const float4*>(p + 4);
    float fv[8] = {f0.x, f0.y, f0.z, f0.w, f1.x, f1.y, f1.z, f1.w};
    half8 h, l;
    float s = 0.0f;
    #pragma unroll
    for (int j = 0; j < 8; ++j) {
        h[j] = (_Float16)fv[j];
        l[j] = (_Float16)(fv[j] - (float)h[j]);
        s += fv[j] * fv[j];
    }
    const int pan = c >> 5, m = c & 31;
    const int lane = g * 32 + m;
    const size_t off = (((size_t)pan * 16 + kc) * 2 + 0) * 64 + lane;  // half8 units
    *reinterpret_cast<half8*>(cbF + off * 8) = h;
    *reinterpret_cast<half8*>(cbF + (off + 64) * 8) = l;               // term=1 (+64 half8)
    #pragma unroll
    for (int d = 16; d; d >>= 1) s += __shfl_xor(s, d);
    if (grp == 0) hn[c] = s;
}

// ---------------------------------------------------------------------------
// Kernel 2: MFMA distance GEMM + argmin.  512 threads, 128 queries/block.
// Queries staged in LDS (fp16 hi/lo fragment-major, kc-XOR-swizzled slots).
// Wave w owns codewords w*128..w*128+127 as 4 sequential panels.
// LDS (140 KB) caps the CU at 1 block = 2 waves/EU, so force the register
// allocator to that occupancy (256 VGPRs) -> no accumulator spill.
// ---------------------------------------------------------------------------
__global__
__attribute__((amdgpu_flat_work_group_size(512, 512), amdgpu_waves_per_eu(2, 2)))
void vq_main(const float* __restrict__ A,          // z_e [MTOT][KDIM] fp32
             const _Float16* __restrict__ cbF,     // fragment-major codebook
             const float* __restrict__ hn,         // [CBSZ] norms
             float* __restrict__ out_idx_f,
             int* __restrict__ out_idx_i) {
    // qF layout (half8 units): [qg(4)][kc(16)][term(2)][slot(64)]
    __shared__ _Float16 qF[4 * 16 * 2 * 64 * 8];   // 128 KB
    __shared__ float hs[CBSZ];                      // 4 KB
    __shared__ float smin[8][128];                  // 4 KB
    __shared__ int   simin[8][128];                 // 4 KB

    const int tid = threadIdx.x;
    const int qbase = blockIdx.x * 128;

    // ---- stage queries: fp32 -> fp16 hi/lo fragments in LDS ----
    #pragma unroll
    for (int it = 0; it < 8; ++it) {
        const int flat = it * 512 + tid;            // 4096 groups
        const int q = flat >> 5;                    // 0..127
        const int grp = flat & 31;
        const int kc = grp >> 1, g = grp & 1;
        const float* p = A + (size_t)(qbase + q) * KDIM + grp * 8;
        float4 f0 = *reinterpret_cast<const float4*>(p);
        float4 f1 = *reinterpret_cast<const float4*>(p + 4);
        float fv[8] = {f0.x, f0.y, f0.z, f0.w, f1.x, f1.y, f1.z, f1.w};
        half8 h, l;
        #pragma unroll
        for (int j = 0; j < 8; ++j) {
            h[j] = (_Float16)fv[j];
            l[j] = (_Float16)(fv[j] - (float)h[j]);
        }
        const int qg = q >> 5;
        const int lw = g * 32 + (q & 31);
        const int sl = lw ^ (kc & 7);               // swizzled 16B slot
        _Float16* dst = qF + (((qg * 16 + kc) * 2 + 0) * 64 + sl) * 8;
        *reinterpret_cast<half8*>(dst) = h;
        *reinterpret_cast<half8*>(dst + 512) = l;   // term=1: +64 half8 = +512 halves
    }
    for (int i = tid; i < CBSZ; i += 512) hs[i] = hn[i];
    __syncthreads();

    const int lane = tid & 63;
    const int wave = tid >> 6;
    const int m31 = lane & 31;
    const int g = lane >> 5;

    float minv[4];
    int   mini[4];
    #pragma unroll
    for (int qg = 0; qg < 4; ++qg) { minv[qg] = 3.4e38f; mini[qg] = 0; }

    for (int pi = 0; pi < 4; ++pi) {
        const int pan = wave * 4 + pi;              // one panel at a time

        f32x16 acc[4];
        #pragma unroll
        for (int qg = 0; qg < 4; ++qg) acc[qg] = (f32x16){};

        // A-fragment address helper (half8 units)
        #define AFRAG(kc_, t_) \
            (*reinterpret_cast<const half8*>(cbF + ((((size_t)pan * 16 + (kc_)) * 2 + (t_)) * 64 + lane) * 8))

        #pragma unroll
        for (int kc = 0; kc < 16; ++kc) {
            half8 Ah = AFRAG(kc, 0);
            half8 Al = AFRAG(kc, 1);
            // B fragments from LDS (swizzled slots)
            const int sl = lane ^ (kc & 7);
            half8 bh[4], bl[4];
            #pragma unroll
            for (int qg = 0; qg < 4; ++qg) {
                const _Float16* qb = qF + (((qg * 16 + kc) * 2 + 0) * 64 + sl) * 8;
                bh[qg] = *reinterpret_cast<const half8*>(qb);
                bl[qg] = *reinterpret_cast<const half8*>(qb + 512);   // +64 half8
            }
            #pragma unroll
            for (int qg = 0; qg < 4; ++qg)
                acc[qg] = __builtin_amdgcn_mfma_f32_32x32x16_f16(Ah, bh[qg], acc[qg], 0, 0, 0);
            #pragma unroll
            for (int qg = 0; qg < 4; ++qg)
                acc[qg] = __builtin_amdgcn_mfma_f32_32x32x16_f16(Al, bh[qg], acc[qg], 0, 0, 0);
            #pragma unroll
            for (int qg = 0; qg < 4; ++qg)
                acc[qg] = __builtin_amdgcn_mfma_f32_32x32x16_f16(Ah, bl[qg], acc[qg], 0, 0, 0);
        }
        #undef AFRAG

        // epilogue: surrogate distance + running argmin (ascending codeword)
        const int cwb = pan * 32 + 4 * g;
        #pragma unroll
        for (int qg = 0; qg < 4; ++qg) {
            #pragma unroll
            for (int r = 0; r < 16; ++r) {
                const int cw = cwb + (r & 3) + 8 * (r >> 2);
                float s = fmaf(-2.0f, acc[qg][r], hs[cw]);
                if (s < minv[qg]) { minv[qg] = s; mini[qg] = cw; }
            }
        }
    }

    // combine the two g-halves (tie -> lower index)
    #pragma unroll
    for (int qg = 0; qg < 4; ++qg) {
        float v = minv[qg]; int ix = mini[qg];
        float ov = __shfl_xor(v, 32);
        int oi = __shfl_xor(ix, 32);
        if (ov < v || (ov == v && oi < ix)) { v = ov; ix = oi; }
        if (g == 0) { smin[wave][qg * 32 + m31] = v; simin[wave][qg * 32 + m31] = ix; }
    }
    __syncthreads();

    // cross-wave reduce: wave order = ascending codeword blocks
    if (tid < 128) {
        float bv = smin[0][tid]; int bi = simin[0][tid];
        #pragma unroll
        for (int w = 1; w < 8; ++w) {
            float v = smin[w][tid]; int ii = simin[w][tid];
            if (v < bv || (v == bv && ii < bi)) { bv = v; bi = ii; }
        }
        out_idx_f[qbase + tid] = (float)bi;
        out_idx_i[qbase + tid] = bi;
    }
}

// ---------------------------------------------------------------------------
// Kernel 3: gather z_q = codebook[idx], per-block loss partials (no atomics).
// ---------------------------------------------------------------------------
#define GATHER_BLOCKS 2048
__global__ void vq_gather(const float* __restrict__ A, const float* __restrict__ cb,
                          const int* __restrict__ idx, float* __restrict__ zq,
                          float* __restrict__ partial) {
    const float4* A4  = reinterpret_cast<const float4*>(A);
    const float4* cb4 = reinterpret_cast<const float4*>(cb);
    float4* zq4 = reinterpret_cast<float4*>(zq);

    const int tg = blockIdx.x * 256 + threadIdx.x;
    float acc = 0.0f;
    #pragma unroll
    for (int it = 0; it < 8; ++it) {
        const size_t gi = (size_t)tg + (size_t)it * (GATHER_BLOCKS * 256);
        const int qq = (int)(gi >> 6);
        const int seg = (int)(gi & 63);
        const int c = idx[qq];                       // wave-uniform
        float4 cv = cb4[(size_t)c * 64 + seg];
        float4 zv = A4[gi];
        zq4[gi] = cv;
        float dx = cv.x - zv.x, dy = cv.y - zv.y, dz = cv.z - zv.z, dw = cv.w - zv.w;
        acc += dx * dx + dy * dy + dz * dz + dw * dw;
    }
    #pragma unroll
    for (int d = 32; d; d >>= 1) acc += __shfl_xor(acc, d);
    __shared__ float ps[4];
    if ((threadIdx.x & 63) == 0) ps[threadIdx.x >> 6] = acc;
    __syncthreads();
    if (threadIdx.x == 0)
        partial[blockIdx.x] = ps[0] + ps[1] + ps[2] + ps[3];
}

// ---------------------------------------------------------------------------
// Kernel 4: reduce partials -> loss = sum / (B*N*D)
// ---------------------------------------------------------------------------
__global__ void vq_finish(const float* __restrict__ partial, float* __restrict__ out_loss) {
    float s = 0.0f;
    #pragma unroll
    for (int it = 0; it < GATHER_BLOCKS / 256; ++it)
        s += partial[threadIdx.x + it * 256];
    #pragma unroll
    for (int d = 32; d; d >>= 1) s += __shfl_xor(s, d);
    __shared__ float ps[4];
    if ((threadIdx.x & 63) == 0) ps[threadIdx.x >> 6] = s;
    __syncthreads();
    if (threadIdx.x == 0)
        *out_loss = (ps[0] + ps[1] + ps[2] + ps[3]) * (1.0f / 16777216.0f);
}

extern "C" void kernel_launch(void* const* d_in, const int* in_sizes, int n_in,
                              void* d_out, int out_size, void* d_ws, size_t ws_size,
                              hipStream_t stream) {
    const float* z_e = (const float*)d_in[0];
    const float* cb  = (const float*)d_in[1];

    float* out   = (float*)d_out;
    float* zq    = out;
    float* oidx  = out + (size_t)MTOT * KDIM;
    float* oloss = out + (size_t)MTOT * KDIM + MTOT;

    char* ws = (char*)d_ws;
    _Float16* cbF = (_Float16*)ws;                               // 1 MB
    float* hn     = (float*)(ws + 1024 * 1024);                  // 4 KB
    int* iidx     = (int*)(ws + 1024 * 1024 + 4096);             // 256 KB
    float* part   = (float*)(ws + 1024 * 1024 + 4096 + 262144);  // 8 KB

    vq_prep<<<128, 256, 0, stream>>>(cb, cbF, hn);
    vq_main<<<MTOT / 128, 512, 0, stream>>>(z_e, cbF, hn, oidx, iidx);
    vq_gather<<<GATHER_BLOCKS, 256, 0, stream>>>(z_e, cb, iidx, zq, part);
    vq_finish<<<1, 256, 0, stream>>>(part, oloss);
}

// Round 7
// 219.873 us; speedup vs baseline: 5.7572x; 2.2082x over previous
//
#include <hip/hip_runtime.h>

#define MTOT (16 * 4096)   // 65536 queries
#define KDIM 256           // vector dim
#define CBSZ 1024          // codebook size

using half8  = _Float16 __attribute__((ext_vector_type(8)));
using f32x16 = float    __attribute__((ext_vector_type(16)));

// ---------------------------------------------------------------------------
// Kernel 1 (prep): codebook -> fragment-major fp16 hi/lo + squared norms.
// cbF layout (half8 units): [panel(32)][kc(16)][term(2)][lane(64)]
//   lane = g*32 + (c&31), holds cb[c][kc*16 + g*8 .. +8]
// ---------------------------------------------------------------------------
__global__ void vq_prep(const float* __restrict__ cb,
                        _Float16* __restrict__ cbF, float* __restrict__ hn) {
    const int flat = blockIdx.x * 256 + threadIdx.x;   // 32768 total
    const int c = flat >> 5;
    const int grp = flat & 31;
    const int kc = grp >> 1, g = grp & 1;
    const float* p = cb + (size_t)c * KDIM + grp * 8;
    float4 f0 = *reinterpret_cast<const float4*>(p);
    float4 f1 = *reinterpret_cast<const float4*>(p + 4);
    float fv[8] = {f0.x, f0.y, f0.z, f0.w, f1.x, f1.y, f1.z, f1.w};
    half8 h, l;
    float s = 0.0f;
    #pragma unroll
    for (int j = 0; j < 8; ++j) {
        h[j] = (_Float16)fv[j];
        l[j] = (_Float16)(fv[j] - (float)h[j]);
        s += fv[j] * fv[j];
    }
    const int pan = c >> 5, m = c & 31;
    const int lane = g * 32 + m;
    const size_t off = (((size_t)pan * 16 + kc) * 2 + 0) * 64 + lane;  // half8 units
    *reinterpret_cast<half8*>(cbF + off * 8) = h;
    *reinterpret_cast<half8*>(cbF + (off + 64) * 8) = l;               // term=1 (+64 half8)
    #pragma unroll
    for (int d = 16; d; d >>= 1) s += __shfl_xor(s, d);
    if (grp == 0) hn[c] = s;
}

// ---------------------------------------------------------------------------
// Kernel 2: MFMA distance GEMM + argmin.  512 threads, 128 queries/block.
// Queries staged in LDS (fp16 hi/lo fragment-major, kc-XOR-swizzled slots).
// Wave w owns codewords w*128..w*128+127 as 4 sequential panels.
// Register economy: qg split into 2 passes of 2 -> acc[2] = 32 VGPRs;
// live set ~100 regs fits the 128-VGPR allocation with no spill.
// (Attributes to raise the budget to 256 were ignored by the allocator in
//  R5/R6 -- restructure instead of fighting it.)
// ---------------------------------------------------------------------------
__global__ __launch_bounds__(512, 2)
void vq_main(const float* __restrict__ A,          // z_e [MTOT][KDIM] fp32
             const _Float16* __restrict__ cbF,     // fragment-major codebook
             const float* __restrict__ hn,         // [CBSZ] norms
             float* __restrict__ out_idx_f,
             int* __restrict__ out_idx_i) {
    // qF layout (half8 units): [qg(4)][kc(16)][term(2)][slot(64)]
    __shared__ _Float16 qF[4 * 16 * 2 * 64 * 8];   // 128 KB
    __shared__ float hs[CBSZ];                      // 4 KB
    __shared__ float smin[8][128];                  // 4 KB
    __shared__ int   simin[8][128];                 // 4 KB

    const int tid = threadIdx.x;
    const int qbase = blockIdx.x * 128;

    // ---- stage queries: fp32 -> fp16 hi/lo fragments in LDS ----
    #pragma unroll
    for (int it = 0; it < 8; ++it) {
        const int flat = it * 512 + tid;            // 4096 groups
        const int q = flat >> 5;                    // 0..127
        const int grp = flat & 31;
        const int kc = grp >> 1, g = grp & 1;
        const float* p = A + (size_t)(qbase + q) * KDIM + grp * 8;
        float4 f0 = *reinterpret_cast<const float4*>(p);
        float4 f1 = *reinterpret_cast<const float4*>(p + 4);
        float fv[8] = {f0.x, f0.y, f0.z, f0.w, f1.x, f1.y, f1.z, f1.w};
        half8 h, l;
        #pragma unroll
        for (int j = 0; j < 8; ++j) {
            h[j] = (_Float16)fv[j];
            l[j] = (_Float16)(fv[j] - (float)h[j]);
        }
        const int qg = q >> 5;
        const int lw = g * 32 + (q & 31);
        const int sl = lw ^ (kc & 7);               // swizzled 16B slot
        _Float16* dst = qF + (((qg * 16 + kc) * 2 + 0) * 64 + sl) * 8;
        *reinterpret_cast<half8*>(dst) = h;
        *reinterpret_cast<half8*>(dst + 512) = l;   // term=1: +64 half8 = +512 halves
    }
    for (int i = tid; i < CBSZ; i += 512) hs[i] = hn[i];
    __syncthreads();

    const int lane = tid & 63;
    const int wave = tid >> 6;
    const int m31 = lane & 31;
    const int g = lane >> 5;

    float minv[4];
    int   mini[4];
    #pragma unroll
    for (int qg = 0; qg < 4; ++qg) { minv[qg] = 3.4e38f; mini[qg] = 0; }

    #pragma unroll
    for (int qp = 0; qp < 2; ++qp) {               // query-group pair pass
        const int qg0 = 2 * qp, qg1 = 2 * qp + 1;

        for (int pi = 0; pi < 4; ++pi) {
            const int pan = wave * 4 + pi;          // one panel at a time

            f32x16 acc0 = (f32x16){};
            f32x16 acc1 = (f32x16){};

            // A-fragment address helper (half8 units)
            #define AFRAG(kc_, t_) \
                (*reinterpret_cast<const half8*>(cbF + ((((size_t)pan * 16 + (kc_)) * 2 + (t_)) * 64 + lane) * 8))

            #pragma unroll
            for (int kc = 0; kc < 16; ++kc) {
                half8 Ah = AFRAG(kc, 0);
                half8 Al = AFRAG(kc, 1);
                const int sl = lane ^ (kc & 7);
                const _Float16* qb0 = qF + (((qg0 * 16 + kc) * 2 + 0) * 64 + sl) * 8;
                const _Float16* qb1 = qF + (((qg1 * 16 + kc) * 2 + 0) * 64 + sl) * 8;
                half8 bh0 = *reinterpret_cast<const half8*>(qb0);
                half8 bl0 = *reinterpret_cast<const half8*>(qb0 + 512);
                half8 bh1 = *reinterpret_cast<const half8*>(qb1);
                half8 bl1 = *reinterpret_cast<const half8*>(qb1 + 512);
                acc0 = __builtin_amdgcn_mfma_f32_32x32x16_f16(Ah, bh0, acc0, 0, 0, 0);
                acc1 = __builtin_amdgcn_mfma_f32_32x32x16_f16(Ah, bh1, acc1, 0, 0, 0);
                acc0 = __builtin_amdgcn_mfma_f32_32x32x16_f16(Al, bh0, acc0, 0, 0, 0);
                acc1 = __builtin_amdgcn_mfma_f32_32x32x16_f16(Al, bh1, acc1, 0, 0, 0);
                acc0 = __builtin_amdgcn_mfma_f32_32x32x16_f16(Ah, bl0, acc0, 0, 0, 0);
                acc1 = __builtin_amdgcn_mfma_f32_32x32x16_f16(Ah, bl1, acc1, 0, 0, 0);
            }
            #undef AFRAG

            // epilogue: surrogate distance + running argmin (ascending codeword)
            const int cwb = pan * 32 + 4 * g;
            #pragma unroll
            for (int r = 0; r < 16; ++r) {
                const int cw = cwb + (r & 3) + 8 * (r >> 2);
                float s0 = fmaf(-2.0f, acc0[r], hs[cw]);
                if (s0 < minv[qg0]) { minv[qg0] = s0; mini[qg0] = cw; }
                float s1 = fmaf(-2.0f, acc1[r], hs[cw]);
                if (s1 < minv[qg1]) { minv[qg1] = s1; mini[qg1] = cw; }
            }
        }
    }

    // combine the two g-halves (tie -> lower index)
    #pragma unroll
    for (int qg = 0; qg < 4; ++qg) {
        float v = minv[qg]; int ix = mini[qg];
        float ov = __shfl_xor(v, 32);
        int oi = __shfl_xor(ix, 32);
        if (ov < v || (ov == v && oi < ix)) { v = ov; ix = oi; }
        if (g == 0) { smin[wave][qg * 32 + m31] = v; simin[wave][qg * 32 + m31] = ix; }
    }
    __syncthreads();

    // cross-wave reduce: wave order = ascending codeword blocks
    if (tid < 128) {
        float bv = smin[0][tid]; int bi = simin[0][tid];
        #pragma unroll
        for (int w = 1; w < 8; ++w) {
            float v = smin[w][tid]; int ii = simin[w][tid];
            if (v < bv || (v == bv && ii < bi)) { bv = v; bi = ii; }
        }
        out_idx_f[qbase + tid] = (float)bi;
        out_idx_i[qbase + tid] = bi;
    }
}

// ---------------------------------------------------------------------------
// Kernel 3: gather z_q = codebook[idx], per-block loss partials (no atomics).
// ---------------------------------------------------------------------------
#define GATHER_BLOCKS 2048
__global__ void vq_gather(const float* __restrict__ A, const float* __restrict__ cb,
                          const int* __restrict__ idx, float* __restrict__ zq,
                          float* __restrict__ partial) {
    const float4* A4  = reinterpret_cast<const float4*>(A);
    const float4* cb4 = reinterpret_cast<const float4*>(cb);
    float4* zq4 = reinterpret_cast<float4*>(zq);

    const int tg = blockIdx.x * 256 + threadIdx.x;
    float acc = 0.0f;
    #pragma unroll
    for (int it = 0; it < 8; ++it) {
        const size_t gi = (size_t)tg + (size_t)it * (GATHER_BLOCKS * 256);
        const int qq = (int)(gi >> 6);
        const int seg = (int)(gi & 63);
        const int c = idx[qq];                       // wave-uniform
        float4 cv = cb4[(size_t)c * 64 + seg];
        float4 zv = A4[gi];
        zq4[gi] = cv;
        float dx = cv.x - zv.x, dy = cv.y - zv.y, dz = cv.z - zv.z, dw = cv.w - zv.w;
        acc += dx * dx + dy * dy + dz * dz + dw * dw;
    }
    #pragma unroll
    for (int d = 32; d; d >>= 1) acc += __shfl_xor(acc, d);
    __shared__ float ps[4];
    if ((threadIdx.x & 63) == 0) ps[threadIdx.x >> 6] = acc;
    __syncthreads();
    if (threadIdx.x == 0)
        partial[blockIdx.x] = ps[0] + ps[1] + ps[2] + ps[3];
}

// ---------------------------------------------------------------------------
// Kernel 4: reduce partials -> loss = sum / (B*N*D)
// ---------------------------------------------------------------------------
__global__ void vq_finish(const float* __restrict__ partial, float* __restrict__ out_loss) {
    float s = 0.0f;
    #pragma unroll
    for (int it = 0; it < GATHER_BLOCKS / 256; ++it)
        s += partial[threadIdx.x + it * 256];
    #pragma unroll
    for (int d = 32; d; d >>= 1) s += __shfl_xor(s, d);
    __shared__ float ps[4];
    if ((threadIdx.x & 63) == 0) ps[threadIdx.x >> 6] = s;
    __syncthreads();
    if (threadIdx.x == 0)
        *out_loss = (ps[0] + ps[1] + ps[2] + ps[3]) * (1.0f / 16777216.0f);
}

extern "C" void kernel_launch(void* const* d_in, const int* in_sizes, int n_in,
                              void* d_out, int out_size, void* d_ws, size_t ws_size,
                              hipStream_t stream) {
    const float* z_e = (const float*)d_in[0];
    const float* cb  = (const float*)d_in[1];

    float* out   = (float*)d_out;
    float* zq    = out;
    float* oidx  = out + (size_t)MTOT * KDIM;
    float* oloss = out + (size_t)MTOT * KDIM + MTOT;

    char* ws = (char*)d_ws;
    _Float16* cbF = (_Float16*)ws;                               // 1 MB
    float* hn     = (float*)(ws + 1024 * 1024);                  // 4 KB
    int* iidx     = (int*)(ws + 1024 * 1024 + 4096);             // 256 KB
    float* part   = (float*)(ws + 1024 * 1024 + 4096 + 262144);  // 8 KB

    vq_prep<<<128, 256, 0, stream>>>(cb, cbF, hn);
    vq_main<<<MTOT / 128, 512, 0, stream>>>(z_e, cbF, hn, oidx, iidx);
    vq_gather<<<GATHER_BLOCKS, 256, 0, stream>>>(z_e, cb, iidx, zq, part);
    vq_finish<<<1, 256, 0, stream>>>(part, oloss);
}

// Round 8
// 144.149 us; speedup vs baseline: 8.7815x; 1.5253x over previous
//
#include <hip/hip_runtime.h>

#define MTOT (16 * 4096)   // 65536 queries
#define KDIM 256           // vector dim
#define CBSZ 1024          // codebook size

using half8  = _Float16 __attribute__((ext_vector_type(8)));
using f32x16 = float    __attribute__((ext_vector_type(16)));

// ---------------------------------------------------------------------------
// Kernel 1 (prep): codebook -> fragment-major fp16 hi/lo + squared norms.
// cbF layout (half8 units): [panel(32)][kc(16)][term(2)][lane(64)]
//   lane = g*32 + (c&31), holds cb[c][kc*16 + g*8 .. +8]
// ---------------------------------------------------------------------------
__global__ void vq_prep(const float* __restrict__ cb,
                        _Float16* __restrict__ cbF, float* __restrict__ hn) {
    const int flat = blockIdx.x * 256 + threadIdx.x;   // 32768 total
    const int c = flat >> 5;
    const int grp = flat & 31;
    const int kc = grp >> 1, g = grp & 1;
    const float* p = cb + (size_t)c * KDIM + grp * 8;
    float4 f0 = *reinterpret_cast<const float4*>(p);
    float4 f1 = *reinterpret_cast<const float4*>(p + 4);
    float fv[8] = {f0.x, f0.y, f0.z, f0.w, f1.x, f1.y, f1.z, f1.w};
    half8 h, l;
    float s = 0.0f;
    #pragma unroll
    for (int j = 0; j < 8; ++j) {
        h[j] = (_Float16)fv[j];
        l[j] = (_Float16)(fv[j] - (float)h[j]);
        s += fv[j] * fv[j];
    }
    const int pan = c >> 5, m = c & 31;
    const int lane = g * 32 + m;
    const size_t off = (((size_t)pan * 16 + kc) * 2 + 0) * 64 + lane;  // half8 units
    *reinterpret_cast<half8*>(cbF + off * 8) = h;
    *reinterpret_cast<half8*>(cbF + (off + 64) * 8) = l;               // term=1 (+64 half8)
    #pragma unroll
    for (int d = 16; d; d >>= 1) s += __shfl_xor(s, d);
    if (grp == 0) hn[c] = s;
}

// ---------------------------------------------------------------------------
// Kernel 2: MFMA distance GEMM + argmin.  512 threads, 64 queries/block.
// Queries staged in LDS (fp16 hi/lo fragment-major, kc-XOR-swizzled slots).
// Wave w owns codewords w*128..w*128+127 as 4 sequential panels; acc0/acc1
// cover the two query-groups in ONE pass (A-fragments read once).
// LDS ~72 KB -> 2 blocks/CU -> 4 waves/SIMD for latency hiding.
// kc loop unrolled x4 only: batches loads without spill-inducing hoisting.
// ---------------------------------------------------------------------------
__global__ __launch_bounds__(512, 2)
void vq_main(const float* __restrict__ A,          // z_e [MTOT][KDIM] fp32
             const _Float16* __restrict__ cbF,     // fragment-major codebook
             const float* __restrict__ hn,         // [CBSZ] norms
             float* __restrict__ out_idx_f,
             int* __restrict__ out_idx_i) {
    // qF layout (half8 units): [qg(2)][kc(16)][term(2)][slot(64)]
    __shared__ _Float16 qF[2 * 16 * 2 * 64 * 8];   // 64 KB
    __shared__ float hs[CBSZ];                      // 4 KB
    __shared__ float smin[8][64];                   // 2 KB
    __shared__ int   simin[8][64];                  // 2 KB

    const int tid = threadIdx.x;
    const int qbase = blockIdx.x * 64;

    // ---- stage queries: fp32 -> fp16 hi/lo fragments in LDS ----
    #pragma unroll
    for (int it = 0; it < 4; ++it) {
        const int flat = it * 512 + tid;            // 2048 groups
        const int q = flat >> 5;                    // 0..63
        const int grp = flat & 31;
        const int kc = grp >> 1, g = grp & 1;
        const float* p = A + (size_t)(qbase + q) * KDIM + grp * 8;
        float4 f0 = *reinterpret_cast<const float4*>(p);
        float4 f1 = *reinterpret_cast<const float4*>(p + 4);
        float fv[8] = {f0.x, f0.y, f0.z, f0.w, f1.x, f1.y, f1.z, f1.w};
        half8 h, l;
        #pragma unroll
        for (int j = 0; j < 8; ++j) {
            h[j] = (_Float16)fv[j];
            l[j] = (_Float16)(fv[j] - (float)h[j]);
        }
        const int qg = q >> 5;
        const int lw = g * 32 + (q & 31);
        const int sl = lw ^ (kc & 7);               // swizzled 16B slot
        _Float16* dst = qF + (((qg * 16 + kc) * 2 + 0) * 64 + sl) * 8;
        *reinterpret_cast<half8*>(dst) = h;
        *reinterpret_cast<half8*>(dst + 512) = l;   // term=1: +64 half8 = +512 halves
    }
    for (int i = tid; i < CBSZ; i += 512) hs[i] = hn[i];
    __syncthreads();

    const int lane = tid & 63;
    const int wave = tid >> 6;
    const int m31 = lane & 31;
    const int g = lane >> 5;

    float minv[2];
    int   mini[2];
    #pragma unroll
    for (int qg = 0; qg < 2; ++qg) { minv[qg] = 3.4e38f; mini[qg] = 0; }

    for (int pi = 0; pi < 4; ++pi) {
        const int pan = wave * 4 + pi;              // one panel at a time

        f32x16 acc0 = (f32x16){};
        f32x16 acc1 = (f32x16){};

        // A-fragment address helper (half8 units)
        #define AFRAG(kc_, t_) \
            (*reinterpret_cast<const half8*>(cbF + ((((size_t)pan * 16 + (kc_)) * 2 + (t_)) * 64 + lane) * 8))

        #pragma unroll 4
        for (int kc = 0; kc < 16; ++kc) {
            half8 Ah = AFRAG(kc, 0);
            half8 Al = AFRAG(kc, 1);
            const int sl = lane ^ (kc & 7);
            const _Float16* qb0 = qF + ((kc * 2 + 0) * 64 + sl) * 8;            // qg0
            const _Float16* qb1 = qF + (((16 + kc) * 2 + 0) * 64 + sl) * 8;     // qg1
            half8 bh0 = *reinterpret_cast<const half8*>(qb0);
            half8 bl0 = *reinterpret_cast<const half8*>(qb0 + 512);
            half8 bh1 = *reinterpret_cast<const half8*>(qb1);
            half8 bl1 = *reinterpret_cast<const half8*>(qb1 + 512);
            acc0 = __builtin_amdgcn_mfma_f32_32x32x16_f16(Ah, bh0, acc0, 0, 0, 0);
            acc1 = __builtin_amdgcn_mfma_f32_32x32x16_f16(Ah, bh1, acc1, 0, 0, 0);
            acc0 = __builtin_amdgcn_mfma_f32_32x32x16_f16(Al, bh0, acc0, 0, 0, 0);
            acc1 = __builtin_amdgcn_mfma_f32_32x32x16_f16(Al, bh1, acc1, 0, 0, 0);
            acc0 = __builtin_amdgcn_mfma_f32_32x32x16_f16(Ah, bl0, acc0, 0, 0, 0);
            acc1 = __builtin_amdgcn_mfma_f32_32x32x16_f16(Ah, bl1, acc1, 0, 0, 0);
        }
        #undef AFRAG

        // epilogue: surrogate distance + running argmin (ascending codeword)
        const int cwb = pan * 32 + 4 * g;
        #pragma unroll
        for (int r = 0; r < 16; ++r) {
            const int cw = cwb + (r & 3) + 8 * (r >> 2);
            float s0 = fmaf(-2.0f, acc0[r], hs[cw]);
            if (s0 < minv[0]) { minv[0] = s0; mini[0] = cw; }
            float s1 = fmaf(-2.0f, acc1[r], hs[cw]);
            if (s1 < minv[1]) { minv[1] = s1; mini[1] = cw; }
        }
    }

    // combine the two g-halves (tie -> lower index)
    #pragma unroll
    for (int qg = 0; qg < 2; ++qg) {
        float v = minv[qg]; int ix = mini[qg];
        float ov = __shfl_xor(v, 32);
        int oi = __shfl_xor(ix, 32);
        if (ov < v || (ov == v && oi < ix)) { v = ov; ix = oi; }
        if (g == 0) { smin[wave][qg * 32 + m31] = v; simin[wave][qg * 32 + m31] = ix; }
    }
    __syncthreads();

    // cross-wave reduce: wave order = ascending codeword blocks
    if (tid < 64) {
        float bv = smin[0][tid]; int bi = simin[0][tid];
        #pragma unroll
        for (int w = 1; w < 8; ++w) {
            float v = smin[w][tid]; int ii = simin[w][tid];
            if (v < bv || (v == bv && ii < bi)) { bv = v; bi = ii; }
        }
        out_idx_f[qbase + tid] = (float)bi;
        out_idx_i[qbase + tid] = bi;
    }
}

// ---------------------------------------------------------------------------
// Kernel 3: gather z_q = codebook[idx], per-block loss partials (no atomics).
// ---------------------------------------------------------------------------
#define GATHER_BLOCKS 2048
__global__ void vq_gather(const float* __restrict__ A, const float* __restrict__ cb,
                          const int* __restrict__ idx, float* __restrict__ zq,
                          float* __restrict__ partial) {
    const float4* A4  = reinterpret_cast<const float4*>(A);
    const float4* cb4 = reinterpret_cast<const float4*>(cb);
    float4* zq4 = reinterpret_cast<float4*>(zq);

    const int tg = blockIdx.x * 256 + threadIdx.x;
    float acc = 0.0f;
    #pragma unroll
    for (int it = 0; it < 8; ++it) {
        const size_t gi = (size_t)tg + (size_t)it * (GATHER_BLOCKS * 256);
        const int qq = (int)(gi >> 6);
        const int seg = (int)(gi & 63);
        const int c = idx[qq];                       // wave-uniform
        float4 cv = cb4[(size_t)c * 64 + seg];
        float4 zv = A4[gi];
        zq4[gi] = cv;
        float dx = cv.x - zv.x, dy = cv.y - zv.y, dz = cv.z - zv.z, dw = cv.w - zv.w;
        acc += dx * dx + dy * dy + dz * dz + dw * dw;
    }
    #pragma unroll
    for (int d = 32; d; d >>= 1) acc += __shfl_xor(acc, d);
    __shared__ float ps[4];
    if ((threadIdx.x & 63) == 0) ps[threadIdx.x >> 6] = acc;
    __syncthreads();
    if (threadIdx.x == 0)
        partial[blockIdx.x] = ps[0] + ps[1] + ps[2] + ps[3];
}

// ---------------------------------------------------------------------------
// Kernel 4: reduce partials -> loss = sum / (B*N*D)
// ---------------------------------------------------------------------------
__global__ void vq_finish(const float* __restrict__ partial, float* __restrict__ out_loss) {
    float s = 0.0f;
    #pragma unroll
    for (int it = 0; it < GATHER_BLOCKS / 256; ++it)
        s += partial[threadIdx.x + it * 256];
    #pragma unroll
    for (int d = 32; d; d >>= 1) s += __shfl_xor(s, d);
    __shared__ float ps[4];
    if ((threadIdx.x & 63) == 0) ps[threadIdx.x >> 6] = s;
    __syncthreads();
    if (threadIdx.x == 0)
        *out_loss = (ps[0] + ps[1] + ps[2] + ps[3]) * (1.0f / 16777216.0f);
}

extern "C" void kernel_launch(void* const* d_in, const int* in_sizes, int n_in,
                              void* d_out, int out_size, void* d_ws, size_t ws_size,
                              hipStream_t stream) {
    const float* z_e = (const float*)d_in[0];
    const float* cb  = (const float*)d_in[1];

    float* out   = (float*)d_out;
    float* zq    = out;
    float* oidx  = out + (size_t)MTOT * KDIM;
    float* oloss = out + (size_t)MTOT * KDIM + MTOT;

    char* ws = (char*)d_ws;
    _Float16* cbF = (_Float16*)ws;                               // 1 MB
    float* hn     = (float*)(ws + 1024 * 1024);                  // 4 KB
    int* iidx     = (int*)(ws + 1024 * 1024 + 4096);             // 256 KB
    float* part   = (float*)(ws + 1024 * 1024 + 4096 + 262144);  // 8 KB

    vq_prep<<<128, 256, 0, stream>>>(cb, cbF, hn);
    vq_main<<<MTOT / 64, 512, 0, stream>>>(z_e, cbF, hn, oidx, iidx);
    vq_gather<<<GATHER_BLOCKS, 256, 0, stream>>>(z_e, cb, iidx, zq, part);
    vq_finish<<<1, 256, 0, stream>>>(part, oloss);
}

// Round 9
// 143.792 us; speedup vs baseline: 8.8033x; 1.0025x over previous
//
#include <hip/hip_runtime.h>

#define MTOT (16 * 4096)   // 65536 queries
#define KDIM 256           // vector dim
#define CBSZ 1024          // codebook size

using half8  = _Float16 __attribute__((ext_vector_type(8)));
using f32x16 = float    __attribute__((ext_vector_type(16)));

// ---------------------------------------------------------------------------
// Kernel 1 (prep): codebook -> fragment-major fp16 hi/lo + squared norms.
// cbF layout (half8 units): [panel(32)][kc(16)][term(2)][lane(64)]
//   lane = g*32 + (c&31), holds cb[c][kc*16 + g*8 .. +8]
// ---------------------------------------------------------------------------
__global__ void vq_prep(const float* __restrict__ cb,
                        _Float16* __restrict__ cbF, float* __restrict__ hn) {
    const int flat = blockIdx.x * 256 + threadIdx.x;   // 32768 total
    const int c = flat >> 5;
    const int grp = flat & 31;
    const int kc = grp >> 1, g = grp & 1;
    const float* p = cb + (size_t)c * KDIM + grp * 8;
    float4 f0 = *reinterpret_cast<const float4*>(p);
    float4 f1 = *reinterpret_cast<const float4*>(p + 4);
    float fv[8] = {f0.x, f0.y, f0.z, f0.w, f1.x, f1.y, f1.z, f1.w};
    half8 h, l;
    float s = 0.0f;
    #pragma unroll
    for (int j = 0; j < 8; ++j) {
        h[j] = (_Float16)fv[j];
        l[j] = (_Float16)(fv[j] - (float)h[j]);
        s += fv[j] * fv[j];
    }
    const int pan = c >> 5, m = c & 31;
    const int lane = g * 32 + m;
    const size_t off = (((size_t)pan * 16 + kc) * 2 + 0) * 64 + lane;  // half8 units
    *reinterpret_cast<half8*>(cbF + off * 8) = h;
    *reinterpret_cast<half8*>(cbF + (off + 64) * 8) = l;               // term=1 (+64 half8)
    #pragma unroll
    for (int d = 16; d; d >>= 1) s += __shfl_xor(s, d);
    if (grp == 0) hn[c] = s;
}

// ---------------------------------------------------------------------------
// Kernel 2: MFMA distance GEMM + argmin.  512 threads, 64 queries/block.
// Queries staged in LDS (fp16 hi/lo fragment-major, kc-XOR-swizzled slots).
// Wave w owns codewords w*128..w*128+127 as 4 sequential panels; acc0/acc1
// cover the two query-groups in ONE pass (A-fragments read once).
// Software-pipelined kc loop: A (global/L2) prefetched at distance 2,
// B (LDS) at distance 1, named rotating registers -> no spill (~105 live).
// ---------------------------------------------------------------------------
__global__ __launch_bounds__(512, 2)
void vq_main(const float* __restrict__ A,          // z_e [MTOT][KDIM] fp32
             const _Float16* __restrict__ cbF,     // fragment-major codebook
             const float* __restrict__ hn,         // [CBSZ] norms
             float* __restrict__ out_idx_f,
             int* __restrict__ out_idx_i) {
    // qF layout (half8 units): [qg(2)][kc(16)][term(2)][slot(64)]
    __shared__ _Float16 qF[2 * 16 * 2 * 64 * 8];   // 64 KB
    __shared__ float hs[CBSZ];                      // 4 KB
    __shared__ float smin[8][64];                   // 2 KB
    __shared__ int   simin[8][64];                  // 2 KB

    const int tid = threadIdx.x;
    const int qbase = blockIdx.x * 64;

    // ---- stage queries: fp32 -> fp16 hi/lo fragments in LDS ----
    #pragma unroll
    for (int it = 0; it < 4; ++it) {
        const int flat = it * 512 + tid;            // 2048 groups
        const int q = flat >> 5;                    // 0..63
        const int grp = flat & 31;
        const int kc = grp >> 1, g = grp & 1;
        const float* p = A + (size_t)(qbase + q) * KDIM + grp * 8;
        float4 f0 = *reinterpret_cast<const float4*>(p);
        float4 f1 = *reinterpret_cast<const float4*>(p + 4);
        float fv[8] = {f0.x, f0.y, f0.z, f0.w, f1.x, f1.y, f1.z, f1.w};
        half8 h, l;
        #pragma unroll
        for (int j = 0; j < 8; ++j) {
            h[j] = (_Float16)fv[j];
            l[j] = (_Float16)(fv[j] - (float)h[j]);
        }
        const int qg = q >> 5;
        const int lw = g * 32 + (q & 31);
        const int sl = lw ^ (kc & 7);               // swizzled 16B slot
        _Float16* dst = qF + (((qg * 16 + kc) * 2 + 0) * 64 + sl) * 8;
        *reinterpret_cast<half8*>(dst) = h;
        *reinterpret_cast<half8*>(dst + 512) = l;   // term=1: +64 half8 = +512 halves
    }
    for (int i = tid; i < CBSZ; i += 512) hs[i] = hn[i];
    __syncthreads();

    const int lane = tid & 63;
    const int wave = tid >> 6;
    const int m31 = lane & 31;
    const int g = lane >> 5;

    float minv[2];
    int   mini[2];
    #pragma unroll
    for (int qg = 0; qg < 2; ++qg) { minv[qg] = 3.4e38f; mini[qg] = 0; }

    for (int pi = 0; pi < 4; ++pi) {
        const int pan = wave * 4 + pi;              // one panel at a time

        f32x16 acc0 = (f32x16){};
        f32x16 acc1 = (f32x16){};

        // A-fragment address helper (half8 units)
        #define AFRAG(kc_, t_) \
            (*reinterpret_cast<const half8*>(cbF + ((((size_t)pan * 16 + (kc_)) * 2 + (t_)) * 64 + lane) * 8))
        #define BPTR(qg_, kc_, sl_) (qF + ((((qg_) * 16 + (kc_)) * 2 + 0) * 64 + (sl_)) * 8)

        // prologue: A(0), A(1); B(0)
        half8 Ah0 = AFRAG(0, 0), Al0 = AFRAG(0, 1);
        half8 Ah1 = AFRAG(1, 0), Al1 = AFRAG(1, 1);
        const int sl00 = lane ^ 0;
        const _Float16* b00 = BPTR(0, 0, sl00);
        const _Float16* b10 = BPTR(1, 0, sl00);
        half8 bh0 = *reinterpret_cast<const half8*>(b00);
        half8 bl0 = *reinterpret_cast<const half8*>(b00 + 512);
        half8 bh1 = *reinterpret_cast<const half8*>(b10);
        half8 bl1 = *reinterpret_cast<const half8*>(b10 + 512);

        #pragma unroll 4
        for (int kc = 0; kc < 16; ++kc) {
            // prefetch A(kc+2) from L2, B(kc+1) from LDS (clamped, no branch)
            const int kA = (kc + 2 < 16) ? kc + 2 : 15;
            half8 pAh = AFRAG(kA, 0);
            half8 pAl = AFRAG(kA, 1);
            const int kB = (kc + 1 < 16) ? kc + 1 : 15;
            const int slB = lane ^ (kB & 7);
            const _Float16* pb0 = BPTR(0, kB, slB);
            const _Float16* pb1 = BPTR(1, kB, slB);
            half8 pbh0 = *reinterpret_cast<const half8*>(pb0);
            half8 pbl0 = *reinterpret_cast<const half8*>(pb0 + 512);
            half8 pbh1 = *reinterpret_cast<const half8*>(pb1);
            half8 pbl1 = *reinterpret_cast<const half8*>(pb1 + 512);

            // compute with current set (order per acc: hh, lh, hl — unchanged)
            acc0 = __builtin_amdgcn_mfma_f32_32x32x16_f16(Ah0, bh0, acc0, 0, 0, 0);
            acc1 = __builtin_amdgcn_mfma_f32_32x32x16_f16(Ah0, bh1, acc1, 0, 0, 0);
            acc0 = __builtin_amdgcn_mfma_f32_32x32x16_f16(Al0, bh0, acc0, 0, 0, 0);
            acc1 = __builtin_amdgcn_mfma_f32_32x32x16_f16(Al0, bh1, acc1, 0, 0, 0);
            acc0 = __builtin_amdgcn_mfma_f32_32x32x16_f16(Ah0, bl0, acc0, 0, 0, 0);
            acc1 = __builtin_amdgcn_mfma_f32_32x32x16_f16(Ah0, bl1, acc1, 0, 0, 0);

            // rotate
            Ah0 = Ah1; Al0 = Al1; Ah1 = pAh; Al1 = pAl;
            bh0 = pbh0; bl0 = pbl0; bh1 = pbh1; bl1 = pbl1;
        }
        #undef AFRAG
        #undef BPTR

        // epilogue: surrogate distance + running argmin (ascending codeword)
        const int cwb = pan * 32 + 4 * g;
        #pragma unroll
        for (int r = 0; r < 16; ++r) {
            const int cw = cwb + (r & 3) + 8 * (r >> 2);
            float s0 = fmaf(-2.0f, acc0[r], hs[cw]);
            if (s0 < minv[0]) { minv[0] = s0; mini[0] = cw; }
            float s1 = fmaf(-2.0f, acc1[r], hs[cw]);
            if (s1 < minv[1]) { minv[1] = s1; mini[1] = cw; }
        }
    }

    // combine the two g-halves (tie -> lower index)
    #pragma unroll
    for (int qg = 0; qg < 2; ++qg) {
        float v = minv[qg]; int ix = mini[qg];
        float ov = __shfl_xor(v, 32);
        int oi = __shfl_xor(ix, 32);
        if (ov < v || (ov == v && oi < ix)) { v = ov; ix = oi; }
        if (g == 0) { smin[wave][qg * 32 + m31] = v; simin[wave][qg * 32 + m31] = ix; }
    }
    __syncthreads();

    // cross-wave reduce: wave order = ascending codeword blocks
    if (tid < 64) {
        float bv = smin[0][tid]; int bi = simin[0][tid];
        #pragma unroll
        for (int w = 1; w < 8; ++w) {
            float v = smin[w][tid]; int ii = simin[w][tid];
            if (v < bv || (v == bv && ii < bi)) { bv = v; bi = ii; }
        }
        out_idx_f[qbase + tid] = (float)bi;
        out_idx_i[qbase + tid] = bi;
    }
}

// ---------------------------------------------------------------------------
// Kernel 3: gather z_q = codebook[idx], per-block loss partials (no atomics).
// ---------------------------------------------------------------------------
#define GATHER_BLOCKS 2048
__global__ void vq_gather(const float* __restrict__ A, const float* __restrict__ cb,
                          const int* __restrict__ idx, float* __restrict__ zq,
                          float* __restrict__ partial) {
    const float4* A4  = reinterpret_cast<const float4*>(A);
    const float4* cb4 = reinterpret_cast<const float4*>(cb);
    float4* zq4 = reinterpret_cast<float4*>(zq);

    const int tg = blockIdx.x * 256 + threadIdx.x;
    float acc = 0.0f;
    #pragma unroll
    for (int it = 0; it < 8; ++it) {
        const size_t gi = (size_t)tg + (size_t)it * (GATHER_BLOCKS * 256);
        const int qq = (int)(gi >> 6);
        const int seg = (int)(gi & 63);
        const int c = idx[qq];                       // wave-uniform
        float4 cv = cb4[(size_t)c * 64 + seg];
        float4 zv = A4[gi];
        zq4[gi] = cv;
        float dx = cv.x - zv.x, dy = cv.y - zv.y, dz = cv.z - zv.z, dw = cv.w - zv.w;
        acc += dx * dx + dy * dy + dz * dz + dw * dw;
    }
    #pragma unroll
    for (int d = 32; d; d >>= 1) acc += __shfl_xor(acc, d);
    __shared__ float ps[4];
    if ((threadIdx.x & 63) == 0) ps[threadIdx.x >> 6] = acc;
    __syncthreads();
    if (threadIdx.x == 0)
        partial[blockIdx.x] = ps[0] + ps[1] + ps[2] + ps[3];
}

// ---------------------------------------------------------------------------
// Kernel 4: reduce partials -> loss = sum / (B*N*D)
// ---------------------------------------------------------------------------
__global__ void vq_finish(const float* __restrict__ partial, float* __restrict__ out_loss) {
    float s = 0.0f;
    #pragma unroll
    for (int it = 0; it < GATHER_BLOCKS / 256; ++it)
        s += partial[threadIdx.x + it * 256];
    #pragma unroll
    for (int d = 32; d; d >>= 1) s += __shfl_xor(s, d);
    __shared__ float ps[4];
    if ((threadIdx.x & 63) == 0) ps[threadIdx.x >> 6] = s;
    __syncthreads();
    if (threadIdx.x == 0)
        *out_loss = (ps[0] + ps[1] + ps[2] + ps[3]) * (1.0f / 16777216.0f);
}

extern "C" void kernel_launch(void* const* d_in, const int* in_sizes, int n_in,
                              void* d_out, int out_size, void* d_ws, size_t ws_size,
                              hipStream_t stream) {
    const float* z_e = (const float*)d_in[0];
    const float* cb  = (const float*)d_in[1];

    float* out   = (float*)d_out;
    float* zq    = out;
    float* oidx  = out + (size_t)MTOT * KDIM;
    float* oloss = out + (size_t)MTOT * KDIM + MTOT;

    char* ws = (char*)d_ws;
    _Float16* cbF = (_Float16*)ws;                               // 1 MB
    float* hn     = (float*)(ws + 1024 * 1024);                  // 4 KB
    int* iidx     = (int*)(ws + 1024 * 1024 + 4096);             // 256 KB
    float* part   = (float*)(ws + 1024 * 1024 + 4096 + 262144);  // 8 KB

    vq_prep<<<128, 256, 0, stream>>>(cb, cbF, hn);
    vq_main<<<MTOT / 64, 512, 0, stream>>>(z_e, cbF, hn, oidx, iidx);
    vq_gather<<<GATHER_BLOCKS, 256, 0, stream>>>(z_e, cb, iidx, zq, part);
    vq_finish<<<1, 256, 0, stream>>>(part, oloss);
}

// Round 10
// 135.817 us; speedup vs baseline: 9.3203x; 1.0587x over previous
//
#include <hip/hip_runtime.h>

#define MTOT (16 * 4096)   // 65536 queries
#define KDIM 256           // vector dim
#define CBSZ 1024          // codebook size

using half8  = _Float16 __attribute__((ext_vector_type(8)));
using f32x16 = float    __attribute__((ext_vector_type(16)));

// ---------------------------------------------------------------------------
// Kernel 1 (prep): codebook -> fragment-major fp16 hi/lo + squared norms.
// cbF layout (half8 units): [panel(32)][kc(16)][term(2)][lane(64)]
//   lane = g*32 + (c&31), holds cb[c][kc*16 + g*8 .. +8]
// ---------------------------------------------------------------------------
__global__ void vq_prep(const float* __restrict__ cb,
                        _Float16* __restrict__ cbF, float* __restrict__ hn) {
    const int flat = blockIdx.x * 256 + threadIdx.x;   // 32768 total
    const int c = flat >> 5;
    const int grp = flat & 31;
    const int kc = grp >> 1, g = grp & 1;
    const float* p = cb + (size_t)c * KDIM + grp * 8;
    float4 f0 = *reinterpret_cast<const float4*>(p);
    float4 f1 = *reinterpret_cast<const float4*>(p + 4);
    float fv[8] = {f0.x, f0.y, f0.z, f0.w, f1.x, f1.y, f1.z, f1.w};
    half8 h, l;
    float s = 0.0f;
    #pragma unroll
    for (int j = 0; j < 8; ++j) {
        h[j] = (_Float16)fv[j];
        l[j] = (_Float16)(fv[j] - (float)h[j]);
        s += fv[j] * fv[j];
    }
    const int pan = c >> 5, m = c & 31;
    const int lane = g * 32 + m;
    const size_t off = (((size_t)pan * 16 + kc) * 2 + 0) * 64 + lane;  // half8 units
    *reinterpret_cast<half8*>(cbF + off * 8) = h;
    *reinterpret_cast<half8*>(cbF + (off + 64) * 8) = l;               // term=1 (+64 half8)
    #pragma unroll
    for (int d = 16; d; d >>= 1) s += __shfl_xor(s, d);
    if (grp == 0) hn[c] = s;
}

// ---------------------------------------------------------------------------
// Kernel 2: MFMA distance GEMM + argmin.  512 threads, 64 queries/block.
// Queries staged in LDS (fp16 hi/lo fragment-major, kc-XOR-swizzled slots).
// Wave w owns codewords w*128..w*128+127 as 2 panel-PAIRS: per kc-iter the
// 2-panel x 2-qg register tile does 12 MFMAs on 4 LDS reads + 4 L2 loads,
// halving LDS-pipe and loop-overhead cost per MFMA vs the single-panel R8.
// acc 64 + A 16 + B 16 + misc ~25 ~= 120 VGPRs -> fits the 128 budget.
// ---------------------------------------------------------------------------
__global__ __launch_bounds__(512, 2)
void vq_main(const float* __restrict__ A,          // z_e [MTOT][KDIM] fp32
             const _Float16* __restrict__ cbF,     // fragment-major codebook
             const float* __restrict__ hn,         // [CBSZ] norms
             float* __restrict__ out_idx_f,
             int* __restrict__ out_idx_i) {
    // qF layout (half8 units): [qg(2)][kc(16)][term(2)][slot(64)]
    __shared__ _Float16 qF[2 * 16 * 2 * 64 * 8];   // 64 KB
    __shared__ float hs[CBSZ];                      // 4 KB
    __shared__ float smin[8][64];                   // 2 KB
    __shared__ int   simin[8][64];                  // 2 KB

    const int tid = threadIdx.x;
    const int qbase = blockIdx.x * 64;

    // ---- stage queries: fp32 -> fp16 hi/lo fragments in LDS ----
    #pragma unroll
    for (int it = 0; it < 4; ++it) {
        const int flat = it * 512 + tid;            // 2048 groups
        const int q = flat >> 5;                    // 0..63
        const int grp = flat & 31;
        const int kc = grp >> 1, g = grp & 1;
        const float* p = A + (size_t)(qbase + q) * KDIM + grp * 8;
        float4 f0 = *reinterpret_cast<const float4*>(p);
        float4 f1 = *reinterpret_cast<const float4*>(p + 4);
        float fv[8] = {f0.x, f0.y, f0.z, f0.w, f1.x, f1.y, f1.z, f1.w};
        half8 h, l;
        #pragma unroll
        for (int j = 0; j < 8; ++j) {
            h[j] = (_Float16)fv[j];
            l[j] = (_Float16)(fv[j] - (float)h[j]);
        }
        const int qg = q >> 5;
        const int lw = g * 32 + (q & 31);
        const int sl = lw ^ (kc & 7);               // swizzled 16B slot
        _Float16* dst = qF + (((qg * 16 + kc) * 2 + 0) * 64 + sl) * 8;
        *reinterpret_cast<half8*>(dst) = h;
        *reinterpret_cast<half8*>(dst + 512) = l;   // term=1: +64 half8 = +512 halves
    }
    for (int i = tid; i < CBSZ; i += 512) hs[i] = hn[i];
    __syncthreads();

    const int lane = tid & 63;
    const int wave = tid >> 6;
    const int m31 = lane & 31;
    const int g = lane >> 5;

    float minv[2];
    int   mini[2];
    #pragma unroll
    for (int qg = 0; qg < 2; ++qg) { minv[qg] = 3.4e38f; mini[qg] = 0; }

    #pragma unroll
    for (int pp = 0; pp < 2; ++pp) {
        const int pa = wave * 4 + pp * 2;           // panel pair pa, pa+1

        f32x16 acc00 = (f32x16){};                  // [panel0][qg0]
        f32x16 acc01 = (f32x16){};                  // [panel0][qg1]
        f32x16 acc10 = (f32x16){};                  // [panel1][qg0]
        f32x16 acc11 = (f32x16){};                  // [panel1][qg1]

        // A-fragment address helper (half8 units)
        #define AFRAG(p_, kc_, t_) \
            (*reinterpret_cast<const half8*>(cbF + ((((size_t)(p_) * 16 + (kc_)) * 2 + (t_)) * 64 + lane) * 8))
        #define BPTR(qg_, kc_, sl_) (qF + ((((qg_) * 16 + (kc_)) * 2 + 0) * 64 + (sl_)) * 8)

        #pragma unroll 2
        for (int kc = 0; kc < 16; ++kc) {
            half8 Ah0 = AFRAG(pa, kc, 0);
            half8 Al0 = AFRAG(pa, kc, 1);
            half8 Ah1 = AFRAG(pa + 1, kc, 0);
            half8 Al1 = AFRAG(pa + 1, kc, 1);
            const int sl = lane ^ (kc & 7);
            const _Float16* qb0 = BPTR(0, kc, sl);
            const _Float16* qb1 = BPTR(1, kc, sl);
            half8 bh0 = *reinterpret_cast<const half8*>(qb0);
            half8 bl0 = *reinterpret_cast<const half8*>(qb0 + 512);
            half8 bh1 = *reinterpret_cast<const half8*>(qb1);
            half8 bl1 = *reinterpret_cast<const half8*>(qb1 + 512);

            // per-acc order: hh, lh, hl (numerics identical to R8/R9)
            acc00 = __builtin_amdgcn_mfma_f32_32x32x16_f16(Ah0, bh0, acc00, 0, 0, 0);
            acc01 = __builtin_amdgcn_mfma_f32_32x32x16_f16(Ah0, bh1, acc01, 0, 0, 0);
            acc10 = __builtin_amdgcn_mfma_f32_32x32x16_f16(Ah1, bh0, acc10, 0, 0, 0);
            acc11 = __builtin_amdgcn_mfma_f32_32x32x16_f16(Ah1, bh1, acc11, 0, 0, 0);
            acc00 = __builtin_amdgcn_mfma_f32_32x32x16_f16(Al0, bh0, acc00, 0, 0, 0);
            acc01 = __builtin_amdgcn_mfma_f32_32x32x16_f16(Al0, bh1, acc01, 0, 0, 0);
            acc10 = __builtin_amdgcn_mfma_f32_32x32x16_f16(Al1, bh0, acc10, 0, 0, 0);
            acc11 = __builtin_amdgcn_mfma_f32_32x32x16_f16(Al1, bh1, acc11, 0, 0, 0);
            acc00 = __builtin_amdgcn_mfma_f32_32x32x16_f16(Ah0, bl0, acc00, 0, 0, 0);
            acc01 = __builtin_amdgcn_mfma_f32_32x32x16_f16(Ah0, bl1, acc01, 0, 0, 0);
            acc10 = __builtin_amdgcn_mfma_f32_32x32x16_f16(Ah1, bl0, acc10, 0, 0, 0);
            acc11 = __builtin_amdgcn_mfma_f32_32x32x16_f16(Ah1, bl1, acc11, 0, 0, 0);
        }
        #undef AFRAG
        #undef BPTR

        // epilogue: surrogate distance + running argmin (ascending codeword:
        // panel pa first, then pa+1; each lane visits its rows ascending)
        const int cwb0 = pa * 32 + 4 * g;
        #pragma unroll
        for (int r = 0; r < 16; ++r) {
            const int cw = cwb0 + (r & 3) + 8 * (r >> 2);
            float s0 = fmaf(-2.0f, acc00[r], hs[cw]);
            if (s0 < minv[0]) { minv[0] = s0; mini[0] = cw; }
            float s1 = fmaf(-2.0f, acc01[r], hs[cw]);
            if (s1 < minv[1]) { minv[1] = s1; mini[1] = cw; }
        }
        const int cwb1 = (pa + 1) * 32 + 4 * g;
        #pragma unroll
        for (int r = 0; r < 16; ++r) {
            const int cw = cwb1 + (r & 3) + 8 * (r >> 2);
            float s0 = fmaf(-2.0f, acc10[r], hs[cw]);
            if (s0 < minv[0]) { minv[0] = s0; mini[0] = cw; }
            float s1 = fmaf(-2.0f, acc11[r], hs[cw]);
            if (s1 < minv[1]) { minv[1] = s1; mini[1] = cw; }
        }
    }

    // combine the two g-halves (tie -> lower index)
    #pragma unroll
    for (int qg = 0; qg < 2; ++qg) {
        float v = minv[qg]; int ix = mini[qg];
        float ov = __shfl_xor(v, 32);
        int oi = __shfl_xor(ix, 32);
        if (ov < v || (ov == v && oi < ix)) { v = ov; ix = oi; }
        if (g == 0) { smin[wave][qg * 32 + m31] = v; simin[wave][qg * 32 + m31] = ix; }
    }
    __syncthreads();

    // cross-wave reduce: wave order = ascending codeword blocks
    if (tid < 64) {
        float bv = smin[0][tid]; int bi = simin[0][tid];
        #pragma unroll
        for (int w = 1; w < 8; ++w) {
            float v = smin[w][tid]; int ii = simin[w][tid];
            if (v < bv || (v == bv && ii < bi)) { bv = v; bi = ii; }
        }
        out_idx_f[qbase + tid] = (float)bi;
        out_idx_i[qbase + tid] = bi;
    }
}

// ---------------------------------------------------------------------------
// Kernel 3: gather z_q = codebook[idx], per-block loss partials (no atomics).
// ---------------------------------------------------------------------------
#define GATHER_BLOCKS 2048
__global__ void vq_gather(const float* __restrict__ A, const float* __restrict__ cb,
                          const int* __restrict__ idx, float* __restrict__ zq,
                          float* __restrict__ partial) {
    const float4* A4  = reinterpret_cast<const float4*>(A);
    const float4* cb4 = reinterpret_cast<const float4*>(cb);
    float4* zq4 = reinterpret_cast<float4*>(zq);

    const int tg = blockIdx.x * 256 + threadIdx.x;
    float acc = 0.0f;
    #pragma unroll
    for (int it = 0; it < 8; ++it) {
        const size_t gi = (size_t)tg + (size_t)it * (GATHER_BLOCKS * 256);
        const int qq = (int)(gi >> 6);
        const int seg = (int)(gi & 63);
        const int c = idx[qq];                       // wave-uniform
        float4 cv = cb4[(size_t)c * 64 + seg];
        float4 zv = A4[gi];
        zq4[gi] = cv;
        float dx = cv.x - zv.x, dy = cv.y - zv.y, dz = cv.z - zv.z, dw = cv.w - zv.w;
        acc += dx * dx + dy * dy + dz * dz + dw * dw;
    }
    #pragma unroll
    for (int d = 32; d; d >>= 1) acc += __shfl_xor(acc, d);
    __shared__ float ps[4];
    if ((threadIdx.x & 63) == 0) ps[threadIdx.x >> 6] = acc;
    __syncthreads();
    if (threadIdx.x == 0)
        partial[blockIdx.x] = ps[0] + ps[1] + ps[2] + ps[3];
}

// ---------------------------------------------------------------------------
// Kernel 4: reduce partials -> loss = sum / (B*N*D)
// ---------------------------------------------------------------------------
__global__ void vq_finish(const float* __restrict__ partial, float* __restrict__ out_loss) {
    float s = 0.0f;
    #pragma unroll
    for (int it = 0; it < GATHER_BLOCKS / 256; ++it)
        s += partial[threadIdx.x + it * 256];
    #pragma unroll
    for (int d = 32; d; d >>= 1) s += __shfl_xor(s, d);
    __shared__ float ps[4];
    if ((threadIdx.x & 63) == 0) ps[threadIdx.x >> 6] = s;
    __syncthreads();
    if (threadIdx.x == 0)
        *out_loss = (ps[0] + ps[1] + ps[2] + ps[3]) * (1.0f / 16777216.0f);
}

extern "C" void kernel_launch(void* const* d_in, const int* in_sizes, int n_in,
                              void* d_out, int out_size, void* d_ws, size_t ws_size,
                              hipStream_t stream) {
    const float* z_e = (const float*)d_in[0];
    const float* cb  = (const float*)d_in[1];

    float* out   = (float*)d_out;
    float* zq    = out;
    float* oidx  = out + (size_t)MTOT * KDIM;
    float* oloss = out + (size_t)MTOT * KDIM + MTOT;

    char* ws = (char*)d_ws;
    _Float16* cbF = (_Float16*)ws;                               // 1 MB
    float* hn     = (float*)(ws + 1024 * 1024);                  // 4 KB
    int* iidx     = (int*)(ws + 1024 * 1024 + 4096);             // 256 KB
    float* part   = (float*)(ws + 1024 * 1024 + 4096 + 262144);  // 8 KB

    vq_prep<<<128, 256, 0, stream>>>(cb, cbF, hn);
    vq_main<<<MTOT / 64, 512, 0, stream>>>(z_e, cbF, hn, oidx, iidx);
    vq_gather<<<GATHER_BLOCKS, 256, 0, stream>>>(z_e, cb, iidx, zq, part);
    vq_finish<<<1, 256, 0, stream>>>(part, oloss);
}